// Round 6
// baseline (549.356 us; speedup 1.0000x reference)
//
#include <hip/hip_runtime.h>
#include <cstdio>
#include <cstdint>

#define N_NODES 50000
#define N_EDGES 500000
#define EMB 128
#define BOND 64
#define NGRAPH 256
#define NB_SCAN ((N_NODES + 255) / 256)   // 196 scan blocks
#define NSTRIP (N_NODES / 16)             // 3125 exact 16-node strips
#define HSTR 136                          // LDS row stride (ushorts): 68 dw = 4 mod 32 banks

typedef short bf16x8 __attribute__((ext_vector_type(8)));   // 8 bf16 (4 VGPRs)
typedef float f32x4  __attribute__((ext_vector_type(4)));

__device__ __forceinline__ unsigned short f2bf(float v){
  unsigned u = __float_as_uint(v);
  unsigned r = (u + 0x7fffu + ((u >> 16) & 1u)) >> 16;  // RNE
  return (unsigned short)r;
}
__device__ __forceinline__ float bf2f(unsigned short u){
  return __uint_as_float(((unsigned)u) << 16);
}

// ---------------- f32 GEMM (node embedding, precision headroom) ----------------
template<int K, int CO, bool BF16OUT>
__global__ __launch_bounds__(256) void gemm_bias(const float* __restrict__ in,
    const float* __restrict__ W, const float* __restrict__ bias,
    void* __restrict__ outp, long M)
{
  constexpr int KC = (K > 64) ? 64 : K;
  constexpr int NKC = K / KC;
  constexpr int LANES = CO / 4;
  constexpr int GROUPS = 256 / LANES;
  constexpr int RPB = GROUPS * 4;
  constexpr int ISTR = K + 1;
  __shared__ float wT[KC * CO];
  __shared__ float inT[RPB * ISTR];
  const int t = threadIdx.x;
  const int lc = t % LANES, g = t / LANES;
  const int c0 = lc * 4;
  const float4 bv = *(const float4*)(bias + c0);

  for (long r0 = (long)blockIdx.x * RPB; r0 < M; r0 += (long)gridDim.x * RPB){
    __syncthreads();
    for (int i = t; i < RPB * K; i += 256){
      int rr = i / K, k = i % K;
      long r = r0 + rr;
      inT[rr * ISTR + k] = (r < M) ? in[r * (long)K + k] : 0.f;
    }
    float acc[4][4];
    #pragma unroll
    for (int rr = 0; rr < 4; rr++){
      acc[rr][0] = bv.x; acc[rr][1] = bv.y; acc[rr][2] = bv.z; acc[rr][3] = bv.w;
    }
    for (int kc = 0; kc < NKC; kc++){
      __syncthreads();
      for (int i = t; i < KC * CO; i += 256){
        int c = i % CO, k = i / CO;
        wT[k * CO + c] = W[c * K + kc * KC + k];
      }
      __syncthreads();
      #pragma unroll 8
      for (int k = 0; k < KC; k++){
        float4 w = *(const float4*)&wT[k * CO + c0];
        #pragma unroll
        for (int rr = 0; rr < 4; rr++){
          float a = inT[(g * 4 + rr) * ISTR + kc * KC + k];
          acc[rr][0] = fmaf(a, w.x, acc[rr][0]);
          acc[rr][1] = fmaf(a, w.y, acc[rr][1]);
          acc[rr][2] = fmaf(a, w.z, acc[rr][2]);
          acc[rr][3] = fmaf(a, w.w, acc[rr][3]);
        }
      }
    }
    #pragma unroll
    for (int rr = 0; rr < 4; rr++){
      long r = r0 + g * 4 + rr;
      if (r < M){
        if (BF16OUT){
          ushort4 o;
          o.x = f2bf(acc[rr][0]); o.y = f2bf(acc[rr][1]);
          o.z = f2bf(acc[rr][2]); o.w = f2bf(acc[rr][3]);
          *(ushort4*)((unsigned short*)outp + r * CO + c0) = o;
        } else {
          float4 o = make_float4(acc[rr][0], acc[rr][1], acc[rr][2], acc[rr][3]);
          *(float4*)((float*)outp + r * CO + c0) = o;
        }
      }
    }
  }
}

// ---------------- bf16 MFMA edge GEMM, CSR-order gather / linear store ----------------
// R5 lesson: pos[]-scattered 2B stores = 4M 32B write transactions (~95us). Invert:
// gather attr rows by cedge[p] (256B full-line reads), write eemb rows linearly.
// C-tile exits via per-wave LDS transform -> 4x contiguous-1KB dwordx4 stores/strip.
__global__ __launch_bounds__(256) void edge_gemm_mfma(
    const float* __restrict__ attr, const float* __restrict__ Wb,
    const float* __restrict__ bb, const int* __restrict__ cedge,
    unsigned short* __restrict__ eemb)
{
  __shared__ unsigned short hs[4][16 * HSTR];   // per-wave C transform tile
  const int t = threadIdx.x;
  const int wv = t >> 6;
  const int l  = t & 63;
  const int lm = l & 15;
  const int q  = l >> 4;
  union U8 { bf16x8 v; unsigned short s[8]; };

  bf16x8 bfrag[8][2];
  float bias[8];
  #pragma unroll
  for (int tn = 0; tn < 8; tn++){
    bias[tn] = bb[tn * 16 + lm];
    #pragma unroll
    for (int h = 0; h < 2; h++){
      const float* wp = Wb + (tn * 16 + lm) * BOND + h * 32 + q * 8;
      float4 w0 = *(const float4*)wp;
      float4 w1 = *(const float4*)(wp + 4);
      U8 u;
      u.s[0] = f2bf(w0.x); u.s[1] = f2bf(w0.y); u.s[2] = f2bf(w0.z); u.s[3] = f2bf(w0.w);
      u.s[4] = f2bf(w1.x); u.s[5] = f2bf(w1.y); u.s[6] = f2bf(w1.z); u.s[7] = f2bf(w1.w);
      bfrag[tn][h] = u.v;
    }
  }

  unsigned short* hw = hs[wv];
  const long stride = (long)gridDim.x * 4 * 16;
  for (long p0 = ((long)blockIdx.x * 4 + wv) * 16; p0 < N_EDGES; p0 += stride){
    // A-row for this lane = CSR-ordered edge id (broadcast across q-groups)
    long eid = (long)cedge[p0 + lm];
    bf16x8 afrag[2];
    #pragma unroll
    for (int h = 0; h < 2; h++){
      const float* ap = attr + eid * BOND + h * 32 + q * 8;
      float4 a0 = *(const float4*)ap;
      float4 a1 = *(const float4*)(ap + 4);
      U8 u;
      u.s[0] = f2bf(a0.x); u.s[1] = f2bf(a0.y); u.s[2] = f2bf(a0.z); u.s[3] = f2bf(a0.w);
      u.s[4] = f2bf(a1.x); u.s[5] = f2bf(a1.y); u.s[6] = f2bf(a1.z); u.s[7] = f2bf(a1.w);
      afrag[h] = u.v;
    }
    // 8 col-tiles; C layout (col=lm, row=q*4+i) -> bf16 -> LDS row-major
    #pragma unroll
    for (int tn = 0; tn < 8; tn++){
      f32x4 acc = {0.f, 0.f, 0.f, 0.f};
      acc = __builtin_amdgcn_mfma_f32_16x16x32_bf16(afrag[0], bfrag[tn][0], acc, 0, 0, 0);
      acc = __builtin_amdgcn_mfma_f32_16x16x32_bf16(afrag[1], bfrag[tn][1], acc, 0, 0, 0);
      #pragma unroll
      for (int i = 0; i < 4; i++)
        hw[(q * 4 + i) * HSTR + tn * 16 + lm] = f2bf(acc[i] + bias[tn]);
    }
    // readback row-major, store 1KB-contiguous per instr (rows p0.. are linear)
    // wave-internal LDS RAW: compiler inserts lgkmcnt wait; per-wave tile, no barrier
    #pragma unroll
    for (int rb = 0; rb < 4; rb++){
      int row = rb * 4 + q;
      ushort4 v0 = *(const ushort4*)(hw + row * HSTR + lm * 8);
      ushort4 v1 = *(const ushort4*)(hw + row * HSTR + lm * 8 + 4);
      unsigned short* op = eemb + (p0 + row) * (long)EMB + lm * 8;
      *(ushort4*)op = v0;
      *(ushort4*)(op + 4) = v1;
    }
  }
}

// ---------------- CSR build (by dst) ----------------

__global__ __launch_bounds__(256) void count_deg(const int* __restrict__ ei,
                                                 int* __restrict__ deg)
{
  int e = blockIdx.x * 256 + threadIdx.x;
  if (e < N_EDGES) atomicAdd(&deg[ei[N_EDGES + e]], 1);
}

__global__ __launch_bounds__(256) void scan_s1(const int* __restrict__ deg,
                                               int* __restrict__ blocksum)
{
  int i = blockIdx.x * 256 + threadIdx.x;
  int lane = threadIdx.x & 63, w = threadIdx.x >> 6;
  int v = (i < N_NODES) ? deg[i] : 0;
  #pragma unroll
  for (int o = 32; o > 0; o >>= 1) v += __shfl_down(v, o, 64);
  __shared__ int ws4[4];
  if (lane == 0) ws4[w] = v;
  __syncthreads();
  if (threadIdx.x == 0) blocksum[blockIdx.x] = ws4[0] + ws4[1] + ws4[2] + ws4[3];
}

__global__ __launch_bounds__(256) void scan_s2(const int* __restrict__ blocksum,
                                               int* __restrict__ blockoff,
                                               int* __restrict__ off)
{
  int t = threadIdx.x;
  int lane = t & 63, w = t >> 6;
  int v = (t < NB_SCAN) ? blocksum[t] : 0;
  int x = v;
  #pragma unroll
  for (int d = 1; d < 64; d <<= 1){
    int y = __shfl_up(x, d, 64);
    if (lane >= d) x += y;
  }
  __shared__ int wsum[4];
  if (lane == 63) wsum[w] = x;
  __syncthreads();
  int wo = 0;
  for (int j = 0; j < w; j++) wo += wsum[j];
  if (t < NB_SCAN) blockoff[t] = wo + x - v;
  if (t == 0) off[N_NODES] = wsum[0] + wsum[1] + wsum[2] + wsum[3];
}

__global__ __launch_bounds__(256) void scan_s3(const int* __restrict__ deg,
    const int* __restrict__ blockoff, int* __restrict__ off, int* __restrict__ fill)
{
  int i = blockIdx.x * 256 + threadIdx.x;
  int lane = threadIdx.x & 63, w = threadIdx.x >> 6;
  int v = (i < N_NODES) ? deg[i] : 0;
  int x = v;
  #pragma unroll
  for (int d = 1; d < 64; d <<= 1){
    int y = __shfl_up(x, d, 64);
    if (lane >= d) x += y;
  }
  __shared__ int wsum[4];
  if (lane == 63) wsum[w] = x;
  __syncthreads();
  int wo = 0;
  for (int j = 0; j < w; j++) wo += wsum[j];
  if (i < N_NODES){
    int excl = blockoff[blockIdx.x] + wo + x - v;
    off[i] = excl;
    fill[i] = excl;
  }
}

// csrc[p] = src node, cedge[p] = edge id   (p = fill[dst]++)
__global__ __launch_bounds__(256) void scatter_edges(const int* __restrict__ ei,
    int* __restrict__ fill, int* __restrict__ csrc, int* __restrict__ cedge)
{
  int e = blockIdx.x * 256 + threadIdx.x;
  if (e < N_EDGES){
    int dst = ei[N_EDGES + e];
    int p = atomicAdd(&fill[dst], 1);
    csrc[p] = ei[e];
    cedge[p] = e;
  }
}

// ---------------- gather aggregation (residual fused, eemb CSR-ordered) ----------------
// 8-deep unroll: 8 independent row-gathers in flight per wave to hide L2/HBM latency.
__global__ __launch_bounds__(256) void agg_kernel(const float* __restrict__ node_old,
    const unsigned short* __restrict__ eemb, const int* __restrict__ off,
    const int* __restrict__ csrc, float* __restrict__ node_new)
{
  int n = blockIdx.x * 8 + (threadIdx.x >> 5);
  if (n >= N_NODES) return;
  int c0 = (threadIdx.x & 31) * 4;
  int s = off[n], e = off[n + 1];
  float4 accA = *(const float4*)(node_old + (long)n * EMB + c0);  // residual
  float4 accB = make_float4(0.f, 0.f, 0.f, 0.f);
  int i = s;
  for (; i + 8 <= e; i += 8){
    int idx[8];
    #pragma unroll
    for (int j = 0; j < 8; j++) idx[j] = csrc[i + j];
    float4 a[8]; ushort4 eb[8];
    #pragma unroll
    for (int j = 0; j < 8; j++){
      a[j]  = *(const float4*)(node_old + (long)idx[j] * EMB + c0);
      eb[j] = *(const ushort4*)(eemb + (long)(i + j) * EMB + c0);
    }
    #pragma unroll
    for (int j = 0; j < 8; j++){
      float4& acc = (j & 1) ? accB : accA;
      acc.x = fmaf(a[j].x, bf2f(eb[j].x), acc.x);
      acc.y = fmaf(a[j].y, bf2f(eb[j].y), acc.y);
      acc.z = fmaf(a[j].z, bf2f(eb[j].z), acc.z);
      acc.w = fmaf(a[j].w, bf2f(eb[j].w), acc.w);
    }
  }
  for (; i < e; i++){
    int src = csrc[i];
    const float4 a = *(const float4*)(node_old + (long)src * EMB + c0);
    ushort4 eb = *(const ushort4*)(eemb + (long)i * EMB + c0);
    accA.x = fmaf(a.x, bf2f(eb.x), accA.x);
    accA.y = fmaf(a.y, bf2f(eb.y), accA.y);
    accA.z = fmaf(a.z, bf2f(eb.z), accA.z);
    accA.w = fmaf(a.w, bf2f(eb.w), accA.w);
  }
  accA.x += accB.x; accA.y += accB.y; accA.z += accB.z; accA.w += accB.w;
  *(float4*)(node_new + (long)n * EMB + c0) = accA;
}

// ---------------- MLP weight prep: fragment-linear bf16 ----------------
__global__ void prep_mlp(const float* __restrict__ W1, const float* __restrict__ W2,
                         unsigned short* __restrict__ w1bf, unsigned short* __restrict__ w2bf)
{
  int i = blockIdx.x * 256 + threadIdx.x;
  if (i < 16384){
    int j = i & 7, lb = (i >> 3) & 63, kc = (i >> 9) & 3, tn = i >> 11;
    int lm = lb & 15, q = lb >> 4;
    w1bf[i] = f2bf(W1[(tn * 16 + lm) * EMB + kc * 32 + q * 8 + j]);
  } else if (i < 16384 + 8192){
    int i2 = i - 16384;
    int j = i2 & 7, lb = (i2 >> 3) & 63, kc = (i2 >> 9) & 3, tc = i2 >> 11;
    int lm = lb & 15, q = lb >> 4;
    w2bf[i2] = f2bf(W2[(tc * 16 + lm) * EMB + kc * 32 + q * 8 + j]);
  }
}

// ---------------- fused MFMA MLP + block-pooled reduction ----------------
__global__ __launch_bounds__(256) void mlp_mfma_pool(const float* __restrict__ ne,
    const unsigned short* __restrict__ w1bf, const unsigned short* __restrict__ w2bf,
    const float* __restrict__ b1, const float* __restrict__ b2,
    const float* __restrict__ W3, const int* __restrict__ batch,
    float* __restrict__ dg)
{
  __shared__ float h1s[4][16 * 132];   // per-wave scratch
  __shared__ float pool[NGRAPH];       // per-block graph accumulator
  const int t = threadIdx.x;
  const int wv = t >> 6, l = t & 63;
  const int lm = l & 15, q = l >> 4;
  union U8 { bf16x8 v; unsigned short s[8]; };

  for (int i = t; i < NGRAPH; i += 256) pool[i] = 0.f;
  __syncthreads();

  const int strip = blockIdx.x * 4 + wv;
  if (strip < NSTRIP){
    const long n0 = (long)strip * 16;

    float b1v[8], b2v[4], w3v[4];
    #pragma unroll
    for (int tn = 0; tn < 8; tn++) b1v[tn] = b1[tn * 16 + lm];
    #pragma unroll
    for (int tc = 0; tc < 4; tc++){ b2v[tc] = b2[tc * 16 + lm]; w3v[tc] = W3[tc * 16 + lm]; }

    bf16x8 a1[4];
    #pragma unroll
    for (int kc = 0; kc < 4; kc++){
      const float* ap = ne + (n0 + lm) * EMB + kc * 32 + q * 8;
      float4 x0 = *(const float4*)ap;
      float4 x1 = *(const float4*)(ap + 4);
      U8 u;
      u.s[0] = f2bf(fmaxf(x0.x, 0.f)); u.s[1] = f2bf(fmaxf(x0.y, 0.f));
      u.s[2] = f2bf(fmaxf(x0.z, 0.f)); u.s[3] = f2bf(fmaxf(x0.w, 0.f));
      u.s[4] = f2bf(fmaxf(x1.x, 0.f)); u.s[5] = f2bf(fmaxf(x1.y, 0.f));
      u.s[6] = f2bf(fmaxf(x1.z, 0.f)); u.s[7] = f2bf(fmaxf(x1.w, 0.f));
      a1[kc] = u.v;
    }

    f32x4 acc1[8];
    #pragma unroll
    for (int tn = 0; tn < 8; tn++) acc1[tn] = (f32x4){b1v[tn], b1v[tn], b1v[tn], b1v[tn]};
    #pragma unroll
    for (int kc = 0; kc < 4; kc++){
      #pragma unroll
      for (int tn = 0; tn < 8; tn++){
        bf16x8 bf = *(const bf16x8*)(w1bf + (size_t)((tn * 4 + kc) * 64 + l) * 8);
        acc1[tn] = __builtin_amdgcn_mfma_f32_16x16x32_bf16(a1[kc], bf, acc1[tn], 0, 0, 0);
      }
    }

    float* h1 = h1s[wv];
    #pragma unroll
    for (int tn = 0; tn < 8; tn++)
      #pragma unroll
      for (int i = 0; i < 4; i++)
        h1[(q * 4 + i) * 132 + tn * 16 + lm] = fmaxf(acc1[tn][i], 0.f);
    bf16x8 a2[4];
    #pragma unroll
    for (int kc = 0; kc < 4; kc++){
      const float* hp = h1 + lm * 132 + kc * 32 + q * 8;
      float4 x0 = *(const float4*)hp;
      float4 x1 = *(const float4*)(hp + 4);
      U8 u;
      u.s[0] = f2bf(x0.x); u.s[1] = f2bf(x0.y); u.s[2] = f2bf(x0.z); u.s[3] = f2bf(x0.w);
      u.s[4] = f2bf(x1.x); u.s[5] = f2bf(x1.y); u.s[6] = f2bf(x1.z); u.s[7] = f2bf(x1.w);
      a2[kc] = u.v;
    }

    f32x4 acc2[4];
    #pragma unroll
    for (int tc = 0; tc < 4; tc++) acc2[tc] = (f32x4){b2v[tc], b2v[tc], b2v[tc], b2v[tc]};
    #pragma unroll
    for (int kc = 0; kc < 4; kc++){
      #pragma unroll
      for (int tc = 0; tc < 4; tc++){
        bf16x8 bf = *(const bf16x8*)(w2bf + (size_t)((tc * 4 + kc) * 64 + l) * 8);
        acc2[tc] = __builtin_amdgcn_mfma_f32_16x16x32_bf16(a2[kc], bf, acc2[tc], 0, 0, 0);
      }
    }

    float e4[4];
    #pragma unroll
    for (int i = 0; i < 4; i++){
      float s = 0.f;
      #pragma unroll
      for (int tc = 0; tc < 4; tc++) s = fmaf(fmaxf(acc2[tc][i], 0.f), w3v[tc], s);
      e4[i] = s;
    }
    #pragma unroll
    for (int m = 1; m < 16; m <<= 1)
      #pragma unroll
      for (int i = 0; i < 4; i++) e4[i] += __shfl_xor(e4[i], m, 64);
    if (lm == 0){
      #pragma unroll
      for (int i = 0; i < 4; i++){
        int node = (int)n0 + q * 4 + i;
        atomicAdd(&pool[batch[node]], e4[i]);
      }
    }
  }
  __syncthreads();
  for (int i = t; i < NGRAPH; i += 256){
    float v = pool[i];
    if (v != 0.f) atomicAdd(&dg[i], v);
  }
}

extern "C" void kernel_launch(void* const* d_in, const int* in_sizes, int n_in,
                              void* d_out, int out_size, void* d_ws, size_t ws_size,
                              hipStream_t stream)
{
  const float* x         = (const float*)d_in[0];
  const float* edge_attr = (const float*)d_in[1];
  const int*   ei        = (const int*)d_in[2];   // [2][E]: row0=src, row1=dst
  const int*   batch     = (const int*)d_in[3];
  const float* Wa = (const float*)d_in[4];
  const float* ba = (const float*)d_in[5];
  const float* Wb = (const float*)d_in[6];
  const float* bb = (const float*)d_in[7];
  const float* W1 = (const float*)d_in[8];
  const float* b1 = (const float*)d_in[9];
  const float* W2 = (const float*)d_in[10];
  const float* b2 = (const float*)d_in[11];
  const float* W3 = (const float*)d_in[12];

  char* ws = (char*)d_ws;
  size_t p = 0;
  auto alloc = [&](size_t bytes) -> char* {
    char* q = ws + p;
    p += (bytes + 255) & ~(size_t)255;
    return q;
  };
  float* bufA = (float*)alloc((size_t)N_NODES * EMB * sizeof(float));          // 25.6 MB
  float* bufB = (float*)alloc((size_t)N_NODES * EMB * sizeof(float));          // 25.6 MB
  unsigned short* eemb = (unsigned short*)alloc((size_t)N_EDGES * EMB * 2);    // 128 MB
  unsigned short* w1bf = (unsigned short*)alloc(16384 * sizeof(short));
  unsigned short* w2bf = (unsigned short*)alloc(8192 * sizeof(short));
  int* deg  = (int*)alloc(N_NODES * sizeof(int));
  int* off  = (int*)alloc((N_NODES + 1) * sizeof(int));
  int* fill = (int*)alloc(N_NODES * sizeof(int));
  int* blocksum = (int*)alloc(NB_SCAN * sizeof(int));
  int* blockoff = (int*)alloc(NB_SCAN * sizeof(int));
  int* csrc  = (int*)alloc((size_t)N_EDGES * sizeof(int));                     // 2 MB
  int* cedge = (int*)alloc((size_t)N_EDGES * sizeof(int));                     // 2 MB
  if (p > ws_size){
    fprintf(stderr, "kernel_launch: ws too small (%zu < %zu)\n", ws_size, p);
    return;
  }

  // CSR build
  hipMemsetAsync(deg, 0, N_NODES * sizeof(int), stream);
  count_deg<<<(N_EDGES + 255) / 256, 256, 0, stream>>>(ei, deg);
  scan_s1<<<NB_SCAN, 256, 0, stream>>>(deg, blocksum);
  scan_s2<<<1, 256, 0, stream>>>(blocksum, blockoff, off);
  scan_s3<<<NB_SCAN, 256, 0, stream>>>(deg, blockoff, off, fill);
  scatter_edges<<<(N_EDGES + 255) / 256, 256, 0, stream>>>(ei, fill, csrc, cedge);

  // Embeddings: node (f32 VALU), edge (bf16 MFMA, CSR-gather, linear store)
  prep_mlp<<<96, 256, 0, stream>>>(W1, W2, w1bf, w2bf);
  gemm_bias<EMB, EMB, false><<<(N_NODES + 31) / 32, 256, 0, stream>>>(x, Wa, ba, bufA, N_NODES);
  edge_gemm_mfma<<<1024, 256, 0, stream>>>(edge_attr, Wb, bb, cedge, eemb);

  // Two message-passing layers, gather-based, residual fused
  agg_kernel<<<(N_NODES + 7) / 8, 256, 0, stream>>>(bufA, eemb, off, csrc, bufB);
  agg_kernel<<<(N_NODES + 7) / 8, 256, 0, stream>>>(bufB, eemb, off, csrc, bufA);

  // Fused MFMA MLP + pool
  hipMemsetAsync(d_out, 0, NGRAPH * sizeof(float), stream);
  mlp_mfma_pool<<<(NSTRIP + 3) / 4, 256, 0, stream>>>(bufA, w1bf, w2bf, b1, b2, W3, batch, (float*)d_out);
}

// Round 7
// 478.409 us; speedup vs baseline: 1.1483x; 1.1483x over previous
//
#include <hip/hip_runtime.h>
#include <cstdio>
#include <cstdint>

#define N_NODES 50000
#define N_EDGES 500000
#define EMB 128
#define BOND 64
#define NGRAPH 256
#define NB_SCAN ((N_NODES + 255) / 256)   // 196 scan blocks
#define NSTRIP (N_NODES / 16)             // 3125 exact 16-node strips
#define HSTR 136                          // LDS row stride (ushorts)

typedef short bf16x8 __attribute__((ext_vector_type(8)));   // 8 bf16 (4 VGPRs)
typedef float f32x4  __attribute__((ext_vector_type(4)));

__device__ __forceinline__ unsigned short f2bf(float v){
  unsigned u = __float_as_uint(v);
  unsigned r = (u + 0x7fffu + ((u >> 16) & 1u)) >> 16;  // RNE
  return (unsigned short)r;
}
__device__ __forceinline__ float bf2f(unsigned short u){
  return __uint_as_float(((unsigned)u) << 16);
}

// ---------------- weight prep: fragment-linear bf16 for Wa, W1, W2 ----------------
// layout: w[((tn*4+kc)*64 + l)*8 + j] = bf16(W[tn*16+lm][kc*32+q*8+j]), l=q*16+lm
__global__ void prep_w(const float* __restrict__ Wa, const float* __restrict__ W1,
                       const float* __restrict__ W2, unsigned short* __restrict__ wabf,
                       unsigned short* __restrict__ w1bf, unsigned short* __restrict__ w2bf)
{
  int i = blockIdx.x * 256 + threadIdx.x;
  int i2 = i & 16383;
  int j = i2 & 7, lb = (i2 >> 3) & 63, kc = (i2 >> 9) & 3, tn = i2 >> 11;
  int lm = lb & 15, q = lb >> 4;
  int row = tn * 16 + lm, col = kc * 32 + q * 8 + j;
  if (i < 16384){
    wabf[i] = f2bf(Wa[row * EMB + col]);
  } else if (i < 32768){
    w1bf[i2] = f2bf(W1[row * EMB + col]);
  } else if (i < 32768 + 8192){
    w2bf[i2] = f2bf(W2[row * EMB + col]);   // tn in [0,4) here (64 rows)
  }
}

// ---------------- bf16 MFMA node-embedding GEMM ----------------
// out[n][c] = f32( sum_k bf16(x[n][k]) * bf16(Wa[c][k]) ) + ba[c]
// Per wave: 16-node strip, 32 MFMAs, direct f32 C store (4x64B segments/instr).
__global__ __launch_bounds__(256) void node_gemm_mfma(const float* __restrict__ x,
    const unsigned short* __restrict__ wabf, const float* __restrict__ ba,
    float* __restrict__ out)
{
  const int t = threadIdx.x;
  const int wv = t >> 6, l = t & 63;
  const int lm = l & 15, q = l >> 4;
  union U8 { bf16x8 v; unsigned short s[8]; };
  const int strip = blockIdx.x * 4 + wv;
  if (strip >= NSTRIP) return;
  const long n0 = (long)strip * 16;

  bf16x8 a[4];
  #pragma unroll
  for (int kc = 0; kc < 4; kc++){
    const float* ap = x + (n0 + lm) * (long)EMB + kc * 32 + q * 8;
    float4 x0 = *(const float4*)ap;
    float4 x1 = *(const float4*)(ap + 4);
    U8 u;
    u.s[0] = f2bf(x0.x); u.s[1] = f2bf(x0.y); u.s[2] = f2bf(x0.z); u.s[3] = f2bf(x0.w);
    u.s[4] = f2bf(x1.x); u.s[5] = f2bf(x1.y); u.s[6] = f2bf(x1.z); u.s[7] = f2bf(x1.w);
    a[kc] = u.v;
  }
  float biasv[8];
  #pragma unroll
  for (int tn = 0; tn < 8; tn++) biasv[tn] = ba[tn * 16 + lm];

  #pragma unroll
  for (int tn = 0; tn < 8; tn++){
    f32x4 acc = {0.f, 0.f, 0.f, 0.f};
    #pragma unroll
    for (int kc = 0; kc < 4; kc++){
      bf16x8 bf = *(const bf16x8*)(wabf + (size_t)((tn * 4 + kc) * 64 + l) * 8);
      acc = __builtin_amdgcn_mfma_f32_16x16x32_bf16(a[kc], bf, acc, 0, 0, 0);
    }
    #pragma unroll
    for (int i = 0; i < 4; i++)
      out[(n0 + q * 4 + i) * (long)EMB + tn * 16 + lm] = acc[i] + biasv[tn];
  }
}

// ---------------- bf16 MFMA edge GEMM, CSR-gather / linear store, 2-strip ----------------
// R6 lesson: 1 outstanding cedge->attr chain per wave caps the random-row stream at
// ~2 TB/s. Process 2 independent 16-row strips per iteration -> 2x in-flight gathers.
__global__ __launch_bounds__(256) void edge_gemm_mfma(
    const float* __restrict__ attr, const float* __restrict__ Wb,
    const float* __restrict__ bb, const int* __restrict__ cedge,
    unsigned short* __restrict__ eemb)
{
  __shared__ unsigned short hs[4][32 * HSTR];   // per-wave C transform tile (2 strips)
  const int t = threadIdx.x;
  const int wv = t >> 6;
  const int l  = t & 63;
  const int lm = l & 15;
  const int q  = l >> 4;
  union U8 { bf16x8 v; unsigned short s[8]; };

  bf16x8 bfrag[8][2];
  float bias[8];
  #pragma unroll
  for (int tn = 0; tn < 8; tn++){
    bias[tn] = bb[tn * 16 + lm];
    #pragma unroll
    for (int h = 0; h < 2; h++){
      const float* wp = Wb + (tn * 16 + lm) * BOND + h * 32 + q * 8;
      float4 w0 = *(const float4*)wp;
      float4 w1 = *(const float4*)(wp + 4);
      U8 u;
      u.s[0] = f2bf(w0.x); u.s[1] = f2bf(w0.y); u.s[2] = f2bf(w0.z); u.s[3] = f2bf(w0.w);
      u.s[4] = f2bf(w1.x); u.s[5] = f2bf(w1.y); u.s[6] = f2bf(w1.z); u.s[7] = f2bf(w1.w);
      bfrag[tn][h] = u.v;
    }
  }

  unsigned short* hw = hs[wv];
  const long stride = (long)gridDim.x * 4 * 32;
  for (long p0 = ((long)blockIdx.x * 4 + wv) * 32; p0 < N_EDGES; p0 += stride){
    // two independent gather chains (500000 % 32 == 0: no tail guards)
    long eidA = (long)cedge[p0 + lm];
    long eidB = (long)cedge[p0 + 16 + lm];
    bf16x8 afA[2], afB[2];
    #pragma unroll
    for (int h = 0; h < 2; h++){
      const float* apA = attr + eidA * BOND + h * 32 + q * 8;
      const float* apB = attr + eidB * BOND + h * 32 + q * 8;
      float4 a0 = *(const float4*)apA;
      float4 a1 = *(const float4*)(apA + 4);
      float4 b0 = *(const float4*)apB;
      float4 b1 = *(const float4*)(apB + 4);
      U8 u;
      u.s[0] = f2bf(a0.x); u.s[1] = f2bf(a0.y); u.s[2] = f2bf(a0.z); u.s[3] = f2bf(a0.w);
      u.s[4] = f2bf(a1.x); u.s[5] = f2bf(a1.y); u.s[6] = f2bf(a1.z); u.s[7] = f2bf(a1.w);
      afA[h] = u.v;
      u.s[0] = f2bf(b0.x); u.s[1] = f2bf(b0.y); u.s[2] = f2bf(b0.z); u.s[3] = f2bf(b0.w);
      u.s[4] = f2bf(b1.x); u.s[5] = f2bf(b1.y); u.s[6] = f2bf(b1.z); u.s[7] = f2bf(b1.w);
      afB[h] = u.v;
    }
    #pragma unroll
    for (int tn = 0; tn < 8; tn++){
      f32x4 accA = {0.f, 0.f, 0.f, 0.f};
      f32x4 accB = {0.f, 0.f, 0.f, 0.f};
      accA = __builtin_amdgcn_mfma_f32_16x16x32_bf16(afA[0], bfrag[tn][0], accA, 0, 0, 0);
      accA = __builtin_amdgcn_mfma_f32_16x16x32_bf16(afA[1], bfrag[tn][1], accA, 0, 0, 0);
      accB = __builtin_amdgcn_mfma_f32_16x16x32_bf16(afB[0], bfrag[tn][0], accB, 0, 0, 0);
      accB = __builtin_amdgcn_mfma_f32_16x16x32_bf16(afB[1], bfrag[tn][1], accB, 0, 0, 0);
      #pragma unroll
      for (int i = 0; i < 4; i++){
        hw[(q * 4 + i) * HSTR + tn * 16 + lm]        = f2bf(accA[i] + bias[tn]);
        hw[(16 + q * 4 + i) * HSTR + tn * 16 + lm]   = f2bf(accB[i] + bias[tn]);
      }
    }
    // linear store: 8 x (4 rows x 256B = 1KB contiguous)
    #pragma unroll
    for (int rb = 0; rb < 8; rb++){
      int row = rb * 4 + q;
      ushort4 v0 = *(const ushort4*)(hw + row * HSTR + lm * 8);
      ushort4 v1 = *(const ushort4*)(hw + row * HSTR + lm * 8 + 4);
      unsigned short* op = eemb + (p0 + row) * (long)EMB + lm * 8;
      *(ushort4*)op = v0;
      *(ushort4*)(op + 4) = v1;
    }
  }
}

// ---------------- CSR build (by dst) ----------------

__global__ __launch_bounds__(256) void count_deg(const int* __restrict__ ei,
                                                 int* __restrict__ deg)
{
  int e = blockIdx.x * 256 + threadIdx.x;
  if (e < N_EDGES) atomicAdd(&deg[ei[N_EDGES + e]], 1);
}

__global__ __launch_bounds__(256) void scan_s1(const int* __restrict__ deg,
                                               int* __restrict__ blocksum)
{
  int i = blockIdx.x * 256 + threadIdx.x;
  int lane = threadIdx.x & 63, w = threadIdx.x >> 6;
  int v = (i < N_NODES) ? deg[i] : 0;
  #pragma unroll
  for (int o = 32; o > 0; o >>= 1) v += __shfl_down(v, o, 64);
  __shared__ int ws4[4];
  if (lane == 0) ws4[w] = v;
  __syncthreads();
  if (threadIdx.x == 0) blocksum[blockIdx.x] = ws4[0] + ws4[1] + ws4[2] + ws4[3];
}

__global__ __launch_bounds__(256) void scan_s2(const int* __restrict__ blocksum,
                                               int* __restrict__ blockoff,
                                               int* __restrict__ off)
{
  int t = threadIdx.x;
  int lane = t & 63, w = t >> 6;
  int v = (t < NB_SCAN) ? blocksum[t] : 0;
  int x = v;
  #pragma unroll
  for (int d = 1; d < 64; d <<= 1){
    int y = __shfl_up(x, d, 64);
    if (lane >= d) x += y;
  }
  __shared__ int wsum[4];
  if (lane == 63) wsum[w] = x;
  __syncthreads();
  int wo = 0;
  for (int j = 0; j < w; j++) wo += wsum[j];
  if (t < NB_SCAN) blockoff[t] = wo + x - v;
  if (t == 0) off[N_NODES] = wsum[0] + wsum[1] + wsum[2] + wsum[3];
}

__global__ __launch_bounds__(256) void scan_s3(const int* __restrict__ deg,
    const int* __restrict__ blockoff, int* __restrict__ off, int* __restrict__ fill)
{
  int i = blockIdx.x * 256 + threadIdx.x;
  int lane = threadIdx.x & 63, w = threadIdx.x >> 6;
  int v = (i < N_NODES) ? deg[i] : 0;
  int x = v;
  #pragma unroll
  for (int d = 1; d < 64; d <<= 1){
    int y = __shfl_up(x, d, 64);
    if (lane >= d) x += y;
  }
  __shared__ int wsum[4];
  if (lane == 63) wsum[w] = x;
  __syncthreads();
  int wo = 0;
  for (int j = 0; j < w; j++) wo += wsum[j];
  if (i < N_NODES){
    int excl = blockoff[blockIdx.x] + wo + x - v;
    off[i] = excl;
    fill[i] = excl;
  }
}

// csrc[p] = src node, cedge[p] = edge id   (p = fill[dst]++)
__global__ __launch_bounds__(256) void scatter_edges(const int* __restrict__ ei,
    int* __restrict__ fill, int* __restrict__ csrc, int* __restrict__ cedge)
{
  int e = blockIdx.x * 256 + threadIdx.x;
  if (e < N_EDGES){
    int dst = ei[N_EDGES + e];
    int p = atomicAdd(&fill[dst], 1);
    csrc[p] = ei[e];
    cedge[p] = e;
  }
}

// ---------------- gather aggregation (residual fused, eemb CSR-ordered) ----------------
__global__ __launch_bounds__(256) void agg_kernel(const float* __restrict__ node_old,
    const unsigned short* __restrict__ eemb, const int* __restrict__ off,
    const int* __restrict__ csrc, float* __restrict__ node_new)
{
  int n = blockIdx.x * 8 + (threadIdx.x >> 5);
  if (n >= N_NODES) return;
  int c0 = (threadIdx.x & 31) * 4;
  int s = off[n], e = off[n + 1];
  float4 accA = *(const float4*)(node_old + (long)n * EMB + c0);  // residual
  float4 accB = make_float4(0.f, 0.f, 0.f, 0.f);
  int i = s;
  for (; i + 8 <= e; i += 8){
    int idx[8];
    #pragma unroll
    for (int j = 0; j < 8; j++) idx[j] = csrc[i + j];
    float4 a[8]; ushort4 eb[8];
    #pragma unroll
    for (int j = 0; j < 8; j++){
      a[j]  = *(const float4*)(node_old + (long)idx[j] * EMB + c0);
      eb[j] = *(const ushort4*)(eemb + (long)(i + j) * EMB + c0);
    }
    #pragma unroll
    for (int j = 0; j < 8; j++){
      float4& acc = (j & 1) ? accB : accA;
      acc.x = fmaf(a[j].x, bf2f(eb[j].x), acc.x);
      acc.y = fmaf(a[j].y, bf2f(eb[j].y), acc.y);
      acc.z = fmaf(a[j].z, bf2f(eb[j].z), acc.z);
      acc.w = fmaf(a[j].w, bf2f(eb[j].w), acc.w);
    }
  }
  for (; i < e; i++){
    int src = csrc[i];
    const float4 a = *(const float4*)(node_old + (long)src * EMB + c0);
    ushort4 eb = *(const ushort4*)(eemb + (long)i * EMB + c0);
    accA.x = fmaf(a.x, bf2f(eb.x), accA.x);
    accA.y = fmaf(a.y, bf2f(eb.y), accA.y);
    accA.z = fmaf(a.z, bf2f(eb.z), accA.z);
    accA.w = fmaf(a.w, bf2f(eb.w), accA.w);
  }
  accA.x += accB.x; accA.y += accB.y; accA.z += accB.z; accA.w += accB.w;
  *(float4*)(node_new + (long)n * EMB + c0) = accA;
}

// ---------------- fused MFMA MLP + block-pooled reduction ----------------
__global__ __launch_bounds__(256) void mlp_mfma_pool(const float* __restrict__ ne,
    const unsigned short* __restrict__ w1bf, const unsigned short* __restrict__ w2bf,
    const float* __restrict__ b1, const float* __restrict__ b2,
    const float* __restrict__ W3, const int* __restrict__ batch,
    float* __restrict__ dg)
{
  __shared__ float h1s[4][16 * 132];   // per-wave scratch
  __shared__ float pool[NGRAPH];       // per-block graph accumulator
  const int t = threadIdx.x;
  const int wv = t >> 6, l = t & 63;
  const int lm = l & 15, q = l >> 4;
  union U8 { bf16x8 v; unsigned short s[8]; };

  for (int i = t; i < NGRAPH; i += 256) pool[i] = 0.f;
  __syncthreads();

  const int strip = blockIdx.x * 4 + wv;
  if (strip < NSTRIP){
    const long n0 = (long)strip * 16;

    float b1v[8], b2v[4], w3v[4];
    #pragma unroll
    for (int tn = 0; tn < 8; tn++) b1v[tn] = b1[tn * 16 + lm];
    #pragma unroll
    for (int tc = 0; tc < 4; tc++){ b2v[tc] = b2[tc * 16 + lm]; w3v[tc] = W3[tc * 16 + lm]; }

    bf16x8 a1[4];
    #pragma unroll
    for (int kc = 0; kc < 4; kc++){
      const float* ap = ne + (n0 + lm) * (long)EMB + kc * 32 + q * 8;
      float4 x0 = *(const float4*)ap;
      float4 x1 = *(const float4*)(ap + 4);
      U8 u;
      u.s[0] = f2bf(fmaxf(x0.x, 0.f)); u.s[1] = f2bf(fmaxf(x0.y, 0.f));
      u.s[2] = f2bf(fmaxf(x0.z, 0.f)); u.s[3] = f2bf(fmaxf(x0.w, 0.f));
      u.s[4] = f2bf(fmaxf(x1.x, 0.f)); u.s[5] = f2bf(fmaxf(x1.y, 0.f));
      u.s[6] = f2bf(fmaxf(x1.z, 0.f)); u.s[7] = f2bf(fmaxf(x1.w, 0.f));
      a1[kc] = u.v;
    }

    f32x4 acc1[8];
    #pragma unroll
    for (int tn = 0; tn < 8; tn++) acc1[tn] = (f32x4){b1v[tn], b1v[tn], b1v[tn], b1v[tn]};
    #pragma unroll
    for (int kc = 0; kc < 4; kc++){
      #pragma unroll
      for (int tn = 0; tn < 8; tn++){
        bf16x8 bf = *(const bf16x8*)(w1bf + (size_t)((tn * 4 + kc) * 64 + l) * 8);
        acc1[tn] = __builtin_amdgcn_mfma_f32_16x16x32_bf16(a1[kc], bf, acc1[tn], 0, 0, 0);
      }
    }

    float* h1 = h1s[wv];
    #pragma unroll
    for (int tn = 0; tn < 8; tn++)
      #pragma unroll
      for (int i = 0; i < 4; i++)
        h1[(q * 4 + i) * 132 + tn * 16 + lm] = fmaxf(acc1[tn][i], 0.f);
    bf16x8 a2[4];
    #pragma unroll
    for (int kc = 0; kc < 4; kc++){
      const float* hp = h1 + lm * 132 + kc * 32 + q * 8;
      float4 x0 = *(const float4*)hp;
      float4 x1 = *(const float4*)(hp + 4);
      U8 u;
      u.s[0] = f2bf(x0.x); u.s[1] = f2bf(x0.y); u.s[2] = f2bf(x0.z); u.s[3] = f2bf(x0.w);
      u.s[4] = f2bf(x1.x); u.s[5] = f2bf(x1.y); u.s[6] = f2bf(x1.z); u.s[7] = f2bf(x1.w);
      a2[kc] = u.v;
    }

    f32x4 acc2[4];
    #pragma unroll
    for (int tc = 0; tc < 4; tc++) acc2[tc] = (f32x4){b2v[tc], b2v[tc], b2v[tc], b2v[tc]};
    #pragma unroll
    for (int kc = 0; kc < 4; kc++){
      #pragma unroll
      for (int tc = 0; tc < 4; tc++){
        bf16x8 bf = *(const bf16x8*)(w2bf + (size_t)((tc * 4 + kc) * 64 + l) * 8);
        acc2[tc] = __builtin_amdgcn_mfma_f32_16x16x32_bf16(a2[kc], bf, acc2[tc], 0, 0, 0);
      }
    }

    float e4[4];
    #pragma unroll
    for (int i = 0; i < 4; i++){
      float s = 0.f;
      #pragma unroll
      for (int tc = 0; tc < 4; tc++) s = fmaf(fmaxf(acc2[tc][i], 0.f), w3v[tc], s);
      e4[i] = s;
    }
    #pragma unroll
    for (int m = 1; m < 16; m <<= 1)
      #pragma unroll
      for (int i = 0; i < 4; i++) e4[i] += __shfl_xor(e4[i], m, 64);
    if (lm == 0){
      #pragma unroll
      for (int i = 0; i < 4; i++){
        int node = (int)n0 + q * 4 + i;
        atomicAdd(&pool[batch[node]], e4[i]);
      }
    }
  }
  __syncthreads();
  for (int i = t; i < NGRAPH; i += 256){
    float v = pool[i];
    if (v != 0.f) atomicAdd(&dg[i], v);
  }
}

extern "C" void kernel_launch(void* const* d_in, const int* in_sizes, int n_in,
                              void* d_out, int out_size, void* d_ws, size_t ws_size,
                              hipStream_t stream)
{
  const float* x         = (const float*)d_in[0];
  const float* edge_attr = (const float*)d_in[1];
  const int*   ei        = (const int*)d_in[2];   // [2][E]: row0=src, row1=dst
  const int*   batch     = (const int*)d_in[3];
  const float* Wa = (const float*)d_in[4];
  const float* ba = (const float*)d_in[5];
  const float* Wb = (const float*)d_in[6];
  const float* bb = (const float*)d_in[7];
  const float* W1 = (const float*)d_in[8];
  const float* b1 = (const float*)d_in[9];
  const float* W2 = (const float*)d_in[10];
  const float* b2 = (const float*)d_in[11];
  const float* W3 = (const float*)d_in[12];

  char* ws = (char*)d_ws;
  size_t p = 0;
  auto alloc = [&](size_t bytes) -> char* {
    char* q = ws + p;
    p += (bytes + 255) & ~(size_t)255;
    return q;
  };
  float* bufA = (float*)alloc((size_t)N_NODES * EMB * sizeof(float));          // 25.6 MB
  float* bufB = (float*)alloc((size_t)N_NODES * EMB * sizeof(float));          // 25.6 MB
  unsigned short* eemb = (unsigned short*)alloc((size_t)N_EDGES * EMB * 2);    // 128 MB
  unsigned short* wabf = (unsigned short*)alloc(16384 * sizeof(short));
  unsigned short* w1bf = (unsigned short*)alloc(16384 * sizeof(short));
  unsigned short* w2bf = (unsigned short*)alloc(8192 * sizeof(short));
  int* deg  = (int*)alloc(N_NODES * sizeof(int));
  int* off  = (int*)alloc((N_NODES + 1) * sizeof(int));
  int* fill = (int*)alloc(N_NODES * sizeof(int));
  int* blocksum = (int*)alloc(NB_SCAN * sizeof(int));
  int* blockoff = (int*)alloc(NB_SCAN * sizeof(int));
  int* csrc  = (int*)alloc((size_t)N_EDGES * sizeof(int));                     // 2 MB
  int* cedge = (int*)alloc((size_t)N_EDGES * sizeof(int));                     // 2 MB
  if (p > ws_size){
    fprintf(stderr, "kernel_launch: ws too small (%zu < %zu)\n", ws_size, p);
    return;
  }

  // CSR build
  hipMemsetAsync(deg, 0, N_NODES * sizeof(int), stream);
  count_deg<<<(N_EDGES + 255) / 256, 256, 0, stream>>>(ei, deg);
  scan_s1<<<NB_SCAN, 256, 0, stream>>>(deg, blocksum);
  scan_s2<<<1, 256, 0, stream>>>(blocksum, blockoff, off);
  scan_s3<<<NB_SCAN, 256, 0, stream>>>(deg, blockoff, off, fill);
  scatter_edges<<<(N_EDGES + 255) / 256, 256, 0, stream>>>(ei, fill, csrc, cedge);

  // Embeddings: both MFMA now
  prep_w<<<160, 256, 0, stream>>>(Wa, W1, W2, wabf, w1bf, w2bf);
  node_gemm_mfma<<<(NSTRIP + 3) / 4, 256, 0, stream>>>(x, wabf, ba, bufA);
  edge_gemm_mfma<<<1024, 256, 0, stream>>>(edge_attr, Wb, bb, cedge, eemb);

  // Two message-passing layers, gather-based, residual fused
  agg_kernel<<<(N_NODES + 7) / 8, 256, 0, stream>>>(bufA, eemb, off, csrc, bufB);
  agg_kernel<<<(N_NODES + 7) / 8, 256, 0, stream>>>(bufB, eemb, off, csrc, bufA);

  // Fused MFMA MLP + pool
  hipMemsetAsync(d_out, 0, NGRAPH * sizeof(float), stream);
  mlp_mfma_pool<<<(NSTRIP + 3) / 4, 256, 0, stream>>>(bufA, w1bf, w2bf, b1, b2, W3, batch, (float*)d_out);
}

// Round 8
// 431.729 us; speedup vs baseline: 1.2725x; 1.1081x over previous
//
#include <hip/hip_runtime.h>
#include <cstdio>
#include <cstdint>

#define N_NODES 50000
#define N_EDGES 500000
#define EMB 128
#define BOND 64
#define NGRAPH 256
#define NB_SCAN ((N_NODES + 255) / 256)   // 196 scan blocks
#define NSTRIP (N_NODES / 16)             // 3125 exact 16-node strips
#define HSTR 136                          // LDS row stride (ushorts)

typedef short bf16x8 __attribute__((ext_vector_type(8)));   // 8 bf16 (4 VGPRs)
typedef float f32x4  __attribute__((ext_vector_type(4)));

__device__ __forceinline__ unsigned short f2bf(float v){
  unsigned u = __float_as_uint(v);
  unsigned r = (u + 0x7fffu + ((u >> 16) & 1u)) >> 16;  // RNE
  return (unsigned short)r;
}
__device__ __forceinline__ float bf2f(unsigned short u){
  return __uint_as_float(((unsigned)u) << 16);
}
__device__ __forceinline__ unsigned short brelu(unsigned short u){
  return (u & 0x8000u) ? (unsigned short)0 : u;   // bf16 relu: sign bit -> 0
}

// ---------------- weight prep: fragment-linear bf16 for Wa, W1, W2 ----------------
__global__ void prep_w(const float* __restrict__ Wa, const float* __restrict__ W1,
                       const float* __restrict__ W2, unsigned short* __restrict__ wabf,
                       unsigned short* __restrict__ w1bf, unsigned short* __restrict__ w2bf)
{
  int i = blockIdx.x * 256 + threadIdx.x;
  int i2 = i & 16383;
  int j = i2 & 7, lb = (i2 >> 3) & 63, kc = (i2 >> 9) & 3, tn = i2 >> 11;
  int lm = lb & 15, q = lb >> 4;
  int row = tn * 16 + lm, col = kc * 32 + q * 8 + j;
  if (i < 16384){
    wabf[i] = f2bf(Wa[row * EMB + col]);
  } else if (i < 32768){
    w1bf[i2] = f2bf(W1[row * EMB + col]);
  } else if (i < 32768 + 8192){
    w2bf[i2] = f2bf(W2[row * EMB + col]);   // tn in [0,4) here (64 rows)
  }
}

// ---------------- bf16 MFMA node-embedding GEMM, bf16 out via LDS transform ----------------
__global__ __launch_bounds__(256) void node_gemm_mfma(const float* __restrict__ x,
    const unsigned short* __restrict__ wabf, const float* __restrict__ ba,
    unsigned short* __restrict__ out)
{
  __shared__ unsigned short hs[4][16 * HSTR];
  const int t = threadIdx.x;
  const int wv = t >> 6, l = t & 63;
  const int lm = l & 15, q = l >> 4;
  union U8 { bf16x8 v; unsigned short s[8]; };
  const int strip = blockIdx.x * 4 + wv;
  if (strip >= NSTRIP) return;
  const long n0 = (long)strip * 16;

  bf16x8 a[4];
  #pragma unroll
  for (int kc = 0; kc < 4; kc++){
    const float* ap = x + (n0 + lm) * (long)EMB + kc * 32 + q * 8;
    float4 x0 = *(const float4*)ap;
    float4 x1 = *(const float4*)(ap + 4);
    U8 u;
    u.s[0] = f2bf(x0.x); u.s[1] = f2bf(x0.y); u.s[2] = f2bf(x0.z); u.s[3] = f2bf(x0.w);
    u.s[4] = f2bf(x1.x); u.s[5] = f2bf(x1.y); u.s[6] = f2bf(x1.z); u.s[7] = f2bf(x1.w);
    a[kc] = u.v;
  }
  float biasv[8];
  #pragma unroll
  for (int tn = 0; tn < 8; tn++) biasv[tn] = ba[tn * 16 + lm];

  unsigned short* hw = hs[wv];
  #pragma unroll
  for (int tn = 0; tn < 8; tn++){
    f32x4 acc = {0.f, 0.f, 0.f, 0.f};
    #pragma unroll
    for (int kc = 0; kc < 4; kc++){
      bf16x8 bf = *(const bf16x8*)(wabf + (size_t)((tn * 4 + kc) * 64 + l) * 8);
      acc = __builtin_amdgcn_mfma_f32_16x16x32_bf16(a[kc], bf, acc, 0, 0, 0);
    }
    #pragma unroll
    for (int i = 0; i < 4; i++)
      hw[(q * 4 + i) * HSTR + tn * 16 + lm] = f2bf(acc[i] + biasv[tn]);
  }
  #pragma unroll
  for (int rb = 0; rb < 4; rb++){
    int row = rb * 4 + q;
    ushort4 v0 = *(const ushort4*)(hw + row * HSTR + lm * 8);
    ushort4 v1 = *(const ushort4*)(hw + row * HSTR + lm * 8 + 4);
    unsigned short* op = out + (n0 + row) * (long)EMB + lm * 8;
    *(ushort4*)op = v0;
    *(ushort4*)(op + 4) = v1;
  }
}

// ---------------- bf16 MFMA edge GEMM, CSR-gather / linear store ----------------
// R7 lesson: per-wave ILP (2 chains) gave only 10% — occupancy is the limiter.
// 128-thread blocks halve LDS/block (17.4 KB) -> ~2x resident waves/CU.
__global__ __launch_bounds__(128) void edge_gemm_mfma(
    const float* __restrict__ attr, const float* __restrict__ Wb,
    const float* __restrict__ bb, const int2* __restrict__ cse,
    unsigned short* __restrict__ eemb)
{
  __shared__ unsigned short hs[2][32 * HSTR];   // per-wave C transform tile (2 strips)
  const int t = threadIdx.x;
  const int wv = t >> 6;
  const int l  = t & 63;
  const int lm = l & 15;
  const int q  = l >> 4;
  union U8 { bf16x8 v; unsigned short s[8]; };

  bf16x8 bfrag[8][2];
  float bias[8];
  #pragma unroll
  for (int tn = 0; tn < 8; tn++){
    bias[tn] = bb[tn * 16 + lm];
    #pragma unroll
    for (int h = 0; h < 2; h++){
      const float* wp = Wb + (tn * 16 + lm) * BOND + h * 32 + q * 8;
      float4 w0 = *(const float4*)wp;
      float4 w1 = *(const float4*)(wp + 4);
      U8 u;
      u.s[0] = f2bf(w0.x); u.s[1] = f2bf(w0.y); u.s[2] = f2bf(w0.z); u.s[3] = f2bf(w0.w);
      u.s[4] = f2bf(w1.x); u.s[5] = f2bf(w1.y); u.s[6] = f2bf(w1.z); u.s[7] = f2bf(w1.w);
      bfrag[tn][h] = u.v;
    }
  }

  unsigned short* hw = hs[wv];
  const long stride = (long)gridDim.x * 2 * 32;
  for (long p0 = ((long)blockIdx.x * 2 + wv) * 32; p0 < N_EDGES; p0 += stride){
    long eidA = (long)cse[p0 + lm].y;
    long eidB = (long)cse[p0 + 16 + lm].y;
    bf16x8 afA[2], afB[2];
    #pragma unroll
    for (int h = 0; h < 2; h++){
      const float* apA = attr + eidA * BOND + h * 32 + q * 8;
      const float* apB = attr + eidB * BOND + h * 32 + q * 8;
      float4 a0 = *(const float4*)apA;
      float4 a1 = *(const float4*)(apA + 4);
      float4 b0 = *(const float4*)apB;
      float4 b1 = *(const float4*)(apB + 4);
      U8 u;
      u.s[0] = f2bf(a0.x); u.s[1] = f2bf(a0.y); u.s[2] = f2bf(a0.z); u.s[3] = f2bf(a0.w);
      u.s[4] = f2bf(a1.x); u.s[5] = f2bf(a1.y); u.s[6] = f2bf(a1.z); u.s[7] = f2bf(a1.w);
      afA[h] = u.v;
      u.s[0] = f2bf(b0.x); u.s[1] = f2bf(b0.y); u.s[2] = f2bf(b0.z); u.s[3] = f2bf(b0.w);
      u.s[4] = f2bf(b1.x); u.s[5] = f2bf(b1.y); u.s[6] = f2bf(b1.z); u.s[7] = f2bf(b1.w);
      afB[h] = u.v;
    }
    #pragma unroll
    for (int tn = 0; tn < 8; tn++){
      f32x4 accA = {0.f, 0.f, 0.f, 0.f};
      f32x4 accB = {0.f, 0.f, 0.f, 0.f};
      accA = __builtin_amdgcn_mfma_f32_16x16x32_bf16(afA[0], bfrag[tn][0], accA, 0, 0, 0);
      accA = __builtin_amdgcn_mfma_f32_16x16x32_bf16(afA[1], bfrag[tn][1], accA, 0, 0, 0);
      accB = __builtin_amdgcn_mfma_f32_16x16x32_bf16(afB[0], bfrag[tn][0], accB, 0, 0, 0);
      accB = __builtin_amdgcn_mfma_f32_16x16x32_bf16(afB[1], bfrag[tn][1], accB, 0, 0, 0);
      #pragma unroll
      for (int i = 0; i < 4; i++){
        hw[(q * 4 + i) * HSTR + tn * 16 + lm]      = f2bf(accA[i] + bias[tn]);
        hw[(16 + q * 4 + i) * HSTR + tn * 16 + lm] = f2bf(accB[i] + bias[tn]);
      }
    }
    #pragma unroll
    for (int rb = 0; rb < 8; rb++){
      int row = rb * 4 + q;
      ushort4 v0 = *(const ushort4*)(hw + row * HSTR + lm * 8);
      ushort4 v1 = *(const ushort4*)(hw + row * HSTR + lm * 8 + 4);
      unsigned short* op = eemb + (p0 + row) * (long)EMB + lm * 8;
      *(ushort4*)op = v0;
      *(ushort4*)(op + 4) = v1;
    }
  }
}

// ---------------- CSR build (by dst) ----------------

__global__ __launch_bounds__(256) void count_deg(const int* __restrict__ ei,
                                                 int* __restrict__ deg)
{
  int e = blockIdx.x * 256 + threadIdx.x;
  if (e < N_EDGES) atomicAdd(&deg[ei[N_EDGES + e]], 1);
}

__global__ __launch_bounds__(256) void scan_s1(const int* __restrict__ deg,
                                               int* __restrict__ blocksum)
{
  int i = blockIdx.x * 256 + threadIdx.x;
  int lane = threadIdx.x & 63, w = threadIdx.x >> 6;
  int v = (i < N_NODES) ? deg[i] : 0;
  #pragma unroll
  for (int o = 32; o > 0; o >>= 1) v += __shfl_down(v, o, 64);
  __shared__ int ws4[4];
  if (lane == 0) ws4[w] = v;
  __syncthreads();
  if (threadIdx.x == 0) blocksum[blockIdx.x] = ws4[0] + ws4[1] + ws4[2] + ws4[3];
}

__global__ __launch_bounds__(256) void scan_s2(const int* __restrict__ blocksum,
                                               int* __restrict__ blockoff,
                                               int* __restrict__ off)
{
  int t = threadIdx.x;
  int lane = t & 63, w = t >> 6;
  int v = (t < NB_SCAN) ? blocksum[t] : 0;
  int x = v;
  #pragma unroll
  for (int d = 1; d < 64; d <<= 1){
    int y = __shfl_up(x, d, 64);
    if (lane >= d) x += y;
  }
  __shared__ int wsum[4];
  if (lane == 63) wsum[w] = x;
  __syncthreads();
  int wo = 0;
  for (int j = 0; j < w; j++) wo += wsum[j];
  if (t < NB_SCAN) blockoff[t] = wo + x - v;
  if (t == 0) off[N_NODES] = wsum[0] + wsum[1] + wsum[2] + wsum[3];
}

__global__ __launch_bounds__(256) void scan_s3(const int* __restrict__ deg,
    const int* __restrict__ blockoff, int* __restrict__ off, int* __restrict__ fill)
{
  int i = blockIdx.x * 256 + threadIdx.x;
  int lane = threadIdx.x & 63, w = threadIdx.x >> 6;
  int v = (i < N_NODES) ? deg[i] : 0;
  int x = v;
  #pragma unroll
  for (int d = 1; d < 64; d <<= 1){
    int y = __shfl_up(x, d, 64);
    if (lane >= d) x += y;
  }
  __shared__ int wsum[4];
  if (lane == 63) wsum[w] = x;
  __syncthreads();
  int wo = 0;
  for (int j = 0; j < w; j++) wo += wsum[j];
  if (i < N_NODES){
    int excl = blockoff[blockIdx.x] + wo + x - v;
    off[i] = excl;
    fill[i] = excl;
  }
}

// cse[p] = {src, edge_id} — single 8B store (was 2 scattered 4B stores)
__global__ __launch_bounds__(256) void scatter_edges(const int* __restrict__ ei,
    int* __restrict__ fill, int2* __restrict__ cse)
{
  int e = blockIdx.x * 256 + threadIdx.x;
  if (e < N_EDGES){
    int dst = ei[N_EDGES + e];
    int p = atomicAdd(&fill[dst], 1);
    cse[p] = make_int2(ei[e], e);
  }
}

// ---------------- gather aggregation, all-bf16 node state ----------------
// node_new[n] = bf16( f32(node_old[n]) + sum f32(node_old[src])*f32(eemb[p]) )
// 32 lanes/node, 4 channels/lane, 8-deep unroll. Gather rows now 256B bf16.
__global__ __launch_bounds__(256) void agg_kernel(const unsigned short* __restrict__ node_old,
    const unsigned short* __restrict__ eemb, const int* __restrict__ off,
    const int2* __restrict__ cse, unsigned short* __restrict__ node_new)
{
  int n = blockIdx.x * 8 + (threadIdx.x >> 5);
  if (n >= N_NODES) return;
  int c0 = (threadIdx.x & 31) * 4;
  int s = off[n], e = off[n + 1];
  ushort4 r = *(const ushort4*)(node_old + (long)n * EMB + c0);
  float4 accA = make_float4(bf2f(r.x), bf2f(r.y), bf2f(r.z), bf2f(r.w));  // residual
  float4 accB = make_float4(0.f, 0.f, 0.f, 0.f);
  int i = s;
  for (; i + 8 <= e; i += 8){
    int idx[8];
    #pragma unroll
    for (int j = 0; j < 8; j++) idx[j] = cse[i + j].x;
    ushort4 a[8], eb[8];
    #pragma unroll
    for (int j = 0; j < 8; j++){
      a[j]  = *(const ushort4*)(node_old + (long)idx[j] * EMB + c0);
      eb[j] = *(const ushort4*)(eemb + (long)(i + j) * EMB + c0);
    }
    #pragma unroll
    for (int j = 0; j < 8; j++){
      float4& acc = (j & 1) ? accB : accA;
      acc.x = fmaf(bf2f(a[j].x), bf2f(eb[j].x), acc.x);
      acc.y = fmaf(bf2f(a[j].y), bf2f(eb[j].y), acc.y);
      acc.z = fmaf(bf2f(a[j].z), bf2f(eb[j].z), acc.z);
      acc.w = fmaf(bf2f(a[j].w), bf2f(eb[j].w), acc.w);
    }
  }
  for (; i < e; i++){
    int src = cse[i].x;
    ushort4 a  = *(const ushort4*)(node_old + (long)src * EMB + c0);
    ushort4 eb = *(const ushort4*)(eemb + (long)i * EMB + c0);
    accA.x = fmaf(bf2f(a.x), bf2f(eb.x), accA.x);
    accA.y = fmaf(bf2f(a.y), bf2f(eb.y), accA.y);
    accA.z = fmaf(bf2f(a.z), bf2f(eb.z), accA.z);
    accA.w = fmaf(bf2f(a.w), bf2f(eb.w), accA.w);
  }
  ushort4 o;
  o.x = f2bf(accA.x + accB.x);
  o.y = f2bf(accA.y + accB.y);
  o.z = f2bf(accA.z + accB.z);
  o.w = f2bf(accA.w + accB.w);
  *(ushort4*)(node_new + (long)n * EMB + c0) = o;
}

// ---------------- fused MFMA MLP + block-pooled reduction (bf16 input) ----------------
__global__ __launch_bounds__(256) void mlp_mfma_pool(const unsigned short* __restrict__ ne,
    const unsigned short* __restrict__ w1bf, const unsigned short* __restrict__ w2bf,
    const float* __restrict__ b1, const float* __restrict__ b2,
    const float* __restrict__ W3, const int* __restrict__ batch,
    float* __restrict__ dg)
{
  __shared__ float h1s[4][16 * 132];   // per-wave scratch
  __shared__ float pool[NGRAPH];       // per-block graph accumulator
  const int t = threadIdx.x;
  const int wv = t >> 6, l = t & 63;
  const int lm = l & 15, q = l >> 4;
  union U8 { bf16x8 v; unsigned short s[8]; };

  for (int i = t; i < NGRAPH; i += 256) pool[i] = 0.f;
  __syncthreads();

  const int strip = blockIdx.x * 4 + wv;
  if (strip < NSTRIP){
    const long n0 = (long)strip * 16;

    float b1v[8], b2v[4], w3v[4];
    #pragma unroll
    for (int tn = 0; tn < 8; tn++) b1v[tn] = b1[tn * 16 + lm];
    #pragma unroll
    for (int tc = 0; tc < 4; tc++){ b2v[tc] = b2[tc * 16 + lm]; w3v[tc] = W3[tc * 16 + lm]; }

    // A-fragments: direct bf16 16B loads + sign-bit relu
    bf16x8 a1[4];
    #pragma unroll
    for (int kc = 0; kc < 4; kc++){
      const unsigned short* ap = ne + (n0 + lm) * (long)EMB + kc * 32 + q * 8;
      ushort4 v0 = *(const ushort4*)ap;
      ushort4 v1 = *(const ushort4*)(ap + 4);
      U8 u;
      u.s[0] = brelu(v0.x); u.s[1] = brelu(v0.y); u.s[2] = brelu(v0.z); u.s[3] = brelu(v0.w);
      u.s[4] = brelu(v1.x); u.s[5] = brelu(v1.y); u.s[6] = brelu(v1.z); u.s[7] = brelu(v1.w);
      a1[kc] = u.v;
    }

    f32x4 acc1[8];
    #pragma unroll
    for (int tn = 0; tn < 8; tn++) acc1[tn] = (f32x4){b1v[tn], b1v[tn], b1v[tn], b1v[tn]};
    #pragma unroll
    for (int kc = 0; kc < 4; kc++){
      #pragma unroll
      for (int tn = 0; tn < 8; tn++){
        bf16x8 bf = *(const bf16x8*)(w1bf + (size_t)((tn * 4 + kc) * 64 + l) * 8);
        acc1[tn] = __builtin_amdgcn_mfma_f32_16x16x32_bf16(a1[kc], bf, acc1[tn], 0, 0, 0);
      }
    }

    float* h1 = h1s[wv];
    #pragma unroll
    for (int tn = 0; tn < 8; tn++)
      #pragma unroll
      for (int i = 0; i < 4; i++)
        h1[(q * 4 + i) * 132 + tn * 16 + lm] = fmaxf(acc1[tn][i], 0.f);
    bf16x8 a2[4];
    #pragma unroll
    for (int kc = 0; kc < 4; kc++){
      const float* hp = h1 + lm * 132 + kc * 32 + q * 8;
      float4 x0 = *(const float4*)hp;
      float4 x1 = *(const float4*)(hp + 4);
      U8 u;
      u.s[0] = f2bf(x0.x); u.s[1] = f2bf(x0.y); u.s[2] = f2bf(x0.z); u.s[3] = f2bf(x0.w);
      u.s[4] = f2bf(x1.x); u.s[5] = f2bf(x1.y); u.s[6] = f2bf(x1.z); u.s[7] = f2bf(x1.w);
      a2[kc] = u.v;
    }

    f32x4 acc2[4];
    #pragma unroll
    for (int tc = 0; tc < 4; tc++) acc2[tc] = (f32x4){b2v[tc], b2v[tc], b2v[tc], b2v[tc]};
    #pragma unroll
    for (int kc = 0; kc < 4; kc++){
      #pragma unroll
      for (int tc = 0; tc < 4; tc++){
        bf16x8 bf = *(const bf16x8*)(w2bf + (size_t)((tc * 4 + kc) * 64 + l) * 8);
        acc2[tc] = __builtin_amdgcn_mfma_f32_16x16x32_bf16(a2[kc], bf, acc2[tc], 0, 0, 0);
      }
    }

    float e4[4];
    #pragma unroll
    for (int i = 0; i < 4; i++){
      float s = 0.f;
      #pragma unroll
      for (int tc = 0; tc < 4; tc++) s = fmaf(fmaxf(acc2[tc][i], 0.f), w3v[tc], s);
      e4[i] = s;
    }
    #pragma unroll
    for (int m = 1; m < 16; m <<= 1)
      #pragma unroll
      for (int i = 0; i < 4; i++) e4[i] += __shfl_xor(e4[i], m, 64);
    if (lm == 0){
      #pragma unroll
      for (int i = 0; i < 4; i++){
        int node = (int)n0 + q * 4 + i;
        atomicAdd(&pool[batch[node]], e4[i]);
      }
    }
  }
  __syncthreads();
  for (int i = t; i < NGRAPH; i += 256){
    float v = pool[i];
    if (v != 0.f) atomicAdd(&dg[i], v);
  }
}

extern "C" void kernel_launch(void* const* d_in, const int* in_sizes, int n_in,
                              void* d_out, int out_size, void* d_ws, size_t ws_size,
                              hipStream_t stream)
{
  const float* x         = (const float*)d_in[0];
  const float* edge_attr = (const float*)d_in[1];
  const int*   ei        = (const int*)d_in[2];   // [2][E]: row0=src, row1=dst
  const int*   batch     = (const int*)d_in[3];
  const float* Wa = (const float*)d_in[4];
  const float* ba = (const float*)d_in[5];
  const float* Wb = (const float*)d_in[6];
  const float* bb = (const float*)d_in[7];
  const float* W1 = (const float*)d_in[8];
  const float* b1 = (const float*)d_in[9];
  const float* W2 = (const float*)d_in[10];
  const float* b2 = (const float*)d_in[11];
  const float* W3 = (const float*)d_in[12];

  char* ws = (char*)d_ws;
  size_t p = 0;
  auto alloc = [&](size_t bytes) -> char* {
    char* q = ws + p;
    p += (bytes + 255) & ~(size_t)255;
    return q;
  };
  unsigned short* bufA = (unsigned short*)alloc((size_t)N_NODES * EMB * 2);    // 12.8 MB
  unsigned short* bufB = (unsigned short*)alloc((size_t)N_NODES * EMB * 2);    // 12.8 MB
  unsigned short* eemb = (unsigned short*)alloc((size_t)N_EDGES * EMB * 2);    // 128 MB
  unsigned short* wabf = (unsigned short*)alloc(16384 * sizeof(short));
  unsigned short* w1bf = (unsigned short*)alloc(16384 * sizeof(short));
  unsigned short* w2bf = (unsigned short*)alloc(8192 * sizeof(short));
  int* deg  = (int*)alloc(N_NODES * sizeof(int));
  int* off  = (int*)alloc((N_NODES + 1) * sizeof(int));
  int* fill = (int*)alloc(N_NODES * sizeof(int));
  int* blocksum = (int*)alloc(NB_SCAN * sizeof(int));
  int* blockoff = (int*)alloc(NB_SCAN * sizeof(int));
  int2* cse = (int2*)alloc((size_t)N_EDGES * sizeof(int2));                    // 4 MB
  if (p > ws_size){
    fprintf(stderr, "kernel_launch: ws too small (%zu < %zu)\n", ws_size, p);
    return;
  }

  // CSR build
  hipMemsetAsync(deg, 0, N_NODES * sizeof(int), stream);
  count_deg<<<(N_EDGES + 255) / 256, 256, 0, stream>>>(ei, deg);
  scan_s1<<<NB_SCAN, 256, 0, stream>>>(deg, blocksum);
  scan_s2<<<1, 256, 0, stream>>>(blocksum, blockoff, off);
  scan_s3<<<NB_SCAN, 256, 0, stream>>>(deg, blockoff, off, fill);
  scatter_edges<<<(N_EDGES + 255) / 256, 256, 0, stream>>>(ei, fill, cse);

  // Embeddings (both MFMA; node out bf16)
  prep_w<<<160, 256, 0, stream>>>(Wa, W1, W2, wabf, w1bf, w2bf);
  node_gemm_mfma<<<(NSTRIP + 3) / 4, 256, 0, stream>>>(x, wabf, ba, bufA);
  edge_gemm_mfma<<<2048, 128, 0, stream>>>(edge_attr, Wb, bb, cse, eemb);

  // Two message-passing layers, gather-based, residual fused, bf16 state
  agg_kernel<<<(N_NODES + 7) / 8, 256, 0, stream>>>(bufA, eemb, off, cse, bufB);
  agg_kernel<<<(N_NODES + 7) / 8, 256, 0, stream>>>(bufB, eemb, off, cse, bufA);

  // Fused MFMA MLP + pool
  hipMemsetAsync(d_out, 0, NGRAPH * sizeof(float), stream);
  mlp_mfma_pool<<<(NSTRIP + 3) / 4, 256, 0, stream>>>(bufA, w1bf, w2bf, b1, b2, W3, batch, (float*)d_out);
}